// Round 1
// baseline (384.991 us; speedup 1.0000x reference)
//
#include <hip/hip_runtime.h>
#include <hip/hip_bf16.h>

typedef unsigned short u16;
typedef unsigned int u32;
using floatx4 = __attribute__((ext_vector_type(4))) float;
using short8  = __attribute__((ext_vector_type(8))) short;
using bf16x8  = __attribute__((ext_vector_type(8))) __bf16;

#define B_ 4096
#define F_ 40
#define E_ 64
#define H_ 4
#define A_ 64
#define C_ 256

__device__ __forceinline__ float bf2f(u16 h) {
  u32 u = ((u32)h) << 16;
  return __builtin_bit_cast(float, u);
}
__device__ __forceinline__ u16 f2bf(float f) {  // RNE via hardware cvt, finite inputs
  return __builtin_bit_cast(u16, (__bf16)f);
}
__device__ __forceinline__ floatx4 mfma16(bf16x8 a, bf16x8 b, floatx4 c) {
  return __builtin_amdgcn_mfma_f32_16x16x32_bf16(a, b, c, 0, 0, 0);
}

// dtype sniff: bf16 weights have sane exponents in all 64 u16s; fp32 data's
// low halves are random bits (expect ~40/64 sane). Threshold 56 (6.6 sigma).
__device__ __forceinline__ bool detect_bf16(const void* Wq) {
  int lane = threadIdx.x & 63;
  u16 w = ((const u16*)Wq)[lane];
  int e = (w >> 7) & 0xFF;
  bool sane = (e == 0) || (e >= 96 && e <= 159);
  return __popcll(__ballot(sane)) >= 56;
}

// fallback: element gather + hi/lo split straight from source weights
__device__ __forceinline__ void gather2(const void* W, bool bf, int stride, int col,
                                        int kc, int q, bf16x8& hi, bf16x8& lo) {
  short8 h8 = {0, 0, 0, 0, 0, 0, 0, 0}, l8 = {0, 0, 0, 0, 0, 0, 0, 0};
  int e0 = kc * 32 + q * 8;
#pragma unroll
  for (int j = 0; j < 8; ++j) {
    long off = (long)(e0 + j) * stride + col;
    float v = bf ? bf2f(((const u16*)W)[off]) : ((const float*)W)[off];
    u16 hh = f2bf(v);
    h8[j] = (short)hh;
    l8[j] = (short)f2bf(v - bf2f(hh));
  }
  hi = __builtin_bit_cast(bf16x8, h8);
  lo = __builtin_bit_cast(bf16x8, l8);
}

// fallback: on-the-fly M = Wq.Wk^T fragment (head-offset pointers), hi/lo split
__device__ __forceinline__ void gatherM2(const void* Wqh, const void* Wkh, bool bf,
                                         int kc, int q, int col, bf16x8& hi, bf16x8& lo) {
  short8 h8 = {0, 0, 0, 0, 0, 0, 0, 0}, l8 = {0, 0, 0, 0, 0, 0, 0, 0};
  int e0 = kc * 32 + q * 8;
#pragma unroll
  for (int j = 0; j < 8; ++j) {
    int e1 = e0 + j;
    float acc = 0.f;
    for (int a = 0; a < 64; ++a) {
      float wq = bf ? bf2f(((const u16*)Wqh)[e1 * 64 + a]) : ((const float*)Wqh)[e1 * 64 + a];
      float wk = bf ? bf2f(((const u16*)Wkh)[col * 64 + a]) : ((const float*)Wkh)[col * 64 + a];
      acc += wq * wk;
    }
    u16 hh = f2bf(acc);
    h8[j] = (short)hh;
    l8[j] = (short)f2bf(acc - bf2f(hh));
  }
  hi = __builtin_bit_cast(bf16x8, h8);
  lo = __builtin_bit_cast(bf16x8, l8);
}

// Pack weights into MFMA B-fragment order.
// ws u16 layout: [MH 16384][ML 16384][VH 16384][ResH 16384]  (65536 u16 = 128 KiB)
// M_h = Wq_h . Wk_h^T  (E x E), computed fp32-exact here, split hi/lo.
// frag(h,t,kc) elem[lane*8+j] = Mat[k = kc*32+(lane>>4)*8+j][col = t*16+(lane&15)]
__global__ void pack_w(const void* __restrict__ Wq, const void* __restrict__ Wk,
                       const void* __restrict__ Wv, const void* __restrict__ Wres,
                       u16* __restrict__ ws) {
  bool bf = detect_bf16(Wq);
  int idx = blockIdx.x * 256 + threadIdx.x;  // 0..49151
  int s = idx >> 14;                         // 0:M, 1:V, 2:Res
  int within = idx & 16383;
  int frag = within >> 9;
  int h = frag >> 3, t = (frag >> 1) & 3, kc = frag & 1;
  int pos = within & 511;
  int lane = pos >> 3, j = pos & 7;
  int q = lane >> 4, r = lane & 15;
  int e = kc * 32 + q * 8 + j;
  int col = t * 16 + r;
  if (s == 0) {
    // M[e][col] = sum_a Wq[h][e][a] * Wk[h][col][a]  (fp32 exact)
    float acc = 0.f;
    if (bf) {
      const u16* wq = (const u16*)Wq + ((long)h * 64 + e) * 64;
      const u16* wk = (const u16*)Wk + ((long)h * 64 + col) * 64;
      for (int a = 0; a < 64; ++a) acc += bf2f(wq[a]) * bf2f(wk[a]);
    } else {
      const float* wq = (const float*)Wq + ((long)h * 64 + e) * 64;
      const float* wk = (const float*)Wk + ((long)h * 64 + col) * 64;
      for (int a = 0; a < 64; ++a) acc += wq[a] * wk[a];
    }
    u16 hi = f2bf(acc);
    ws[idx] = hi;                                // MH
    ws[idx + 16384] = f2bf(acc - bf2f(hi));      // ML
  } else {
    const void* src;
    long off;
    if (s == 1) { src = Wv;   off = ((long)h * 64 + e) * 64 + col; }
    else        { src = Wres; off = (long)e * 256 + h * 64 + col; }
    float v = bf ? bf2f(((const u16*)src)[off]) : ((const float*)src)[off];
    ws[idx + 16384] = f2bf(v);  // s=1 -> [32768,49152) VH ; s=2 -> [49152,65536) ResH
  }
}

// One block = one (batch b, head h). 4 waves, 2 barriers.
// S = Q.K^T = X.(Wq.Wk^T).X^T : wave w projects T = X.M column-tile nt=w (split bf16)
// and V^T a-tile w. Then waves 0-2 own f-row-tile mt=w: S = T.X^T (X frags from regs
// as B operand -> no K staging), softmax, P (same-wave LDS round-trip), residual in
// fp32 accumulators (no R buffer, no third barrier), O = P.V + R, relu, store.
template <bool USEWS>
__global__ __launch_bounds__(256, 4) void autoint_attn(
    const void* __restrict__ Xv, const void* __restrict__ Wq,
    const void* __restrict__ Wk, const void* __restrict__ Wv,
    const void* __restrict__ Wres, const u16* __restrict__ wp,
    void* __restrict__ outv) {
  __shared__ __align__(16) u16 smem[17664];  // 35328 B -> 4 blocks/CU
  const int tid = threadIdx.x;
  // XCD-friendly decode: all 4 heads of a batch b map to blockIdx values that are
  // congruent mod 8 and adjacent in dispatch order -> X[b] stays in one XCD's L2.
  const int blk = blockIdx.x;
  const int b = ((blk >> 5) << 3) | (blk & 7);
  const int h = (blk >> 3) & 3;
  const int w = tid >> 6, lane = tid & 63;
  const int q = lane >> 4, r = lane & 15;
  const bool bf = detect_bf16(Wq);

  u16* XH = smem;             // [3 mt][2 kc][64 lane][8]  3072 u16
  u16* XL = smem + 3072;      // 3072
  u16* TH = smem + 6144;      // [48][72]  3456 (aliased by P later, own rows only)
  u16* TL = smem + 9600;      // 3456
  u16* VT = smem + 13056;     // [64][72]  4608

  const u16* PMH = wp;
  const u16* PML = wp + 16384;
  const u16* PVH = wp + 32768;
  const u16* PRH = wp + 49152;

  // ---- issue weight-frag global loads early (L2-hot, hide under X staging) ----
  bf16x8 mh[2], ml[2], wvf[2];
  if constexpr (USEWS) {
#pragma unroll
    for (int kc = 0; kc < 2; ++kc) {
      mh[kc]  = *(const bf16x8*)(PMH + ((h * 4 + w) * 2 + kc) * 512 + lane * 8);
      ml[kc]  = *(const bf16x8*)(PML + ((h * 4 + w) * 2 + kc) * 512 + lane * 8);
      wvf[kc] = *(const bf16x8*)(PVH + ((h * 4 + w) * 2 + kc) * 512 + lane * 8);
    }
  }

  // ---- stage X into split A-frag layout (pad rows 40..47 = 0) ----
  for (int c = tid; c < 384; c += 256) {
    short8 hi8 = {0, 0, 0, 0, 0, 0, 0, 0}, lo8 = {0, 0, 0, 0, 0, 0, 0, 0};
    int f, ec;
    if (c < 320) {
      f = c >> 3; ec = c & 7;
      if (bf) {
        hi8 = *(const short8*)((const u16*)Xv + ((size_t)b * F_ + f) * E_ + ec * 8);
      } else {
        const float* xp = (const float*)Xv + ((size_t)b * F_ + f) * E_ + ec * 8;
        float4 p0 = *(const float4*)xp;
        float4 p1 = *(const float4*)(xp + 4);
        float vals[8] = {p0.x, p0.y, p0.z, p0.w, p1.x, p1.y, p1.z, p1.w};
#pragma unroll
        for (int j = 0; j < 8; ++j) {
          u16 hh = f2bf(vals[j]);
          hi8[j] = (short)hh;
          lo8[j] = (short)f2bf(vals[j] - bf2f(hh));
        }
      }
    } else {
      f = 40 + ((c - 320) >> 3); ec = c & 7;
    }
    int mt = f >> 4, rr = f & 15, kc = ec >> 2, qq = ec & 3;
    int base = ((mt * 2 + kc) * 64 + qq * 16 + rr) * 8;
    *(short8*)(XH + base) = hi8;
    *(short8*)(XL + base) = lo8;
  }
  __syncthreads();

  bf16x8 xh[3][2], xl[3][2];
#pragma unroll
  for (int mt = 0; mt < 3; ++mt)
#pragma unroll
    for (int kc = 0; kc < 2; ++kc) {
      xh[mt][kc] = *(const bf16x8*)(XH + ((mt * 2 + kc) * 64 + lane) * 8);
      xl[mt][kc] = *(const bf16x8*)(XL + ((mt * 2 + kc) * 64 + lane) * 8);
    }

  if constexpr (!USEWS) {
    const void* Wq_p = bf ? (const void*)((const u16*)Wq + h * 4096)
                          : (const void*)((const float*)Wq + h * 4096);
    const void* Wk_p = bf ? (const void*)((const u16*)Wk + h * 4096)
                          : (const void*)((const float*)Wk + h * 4096);
    const void* Wv_p = bf ? (const void*)((const u16*)Wv + h * 4096)
                          : (const void*)((const float*)Wv + h * 4096);
    for (int kc = 0; kc < 2; ++kc) {
      gatherM2(Wq_p, Wk_p, bf, kc, q, w * 16 + r, mh[kc], ml[kc]);
      bf16x8 d;
      gather2(Wv_p, bf, 64, w * 16 + r, kc, q, wvf[kc], d);
    }
  }

  // ---- Phase 1: T = X.M, column tile nt = w, split result into TH/TL ----
  {
    const int nt = w;
#pragma unroll
    for (int mt = 0; mt < 3; ++mt) {
      floatx4 at = {0.f, 0.f, 0.f, 0.f};
#pragma unroll
      for (int kc = 0; kc < 2; ++kc) {
        at = mfma16(xh[mt][kc], mh[kc], at);
        at = mfma16(xh[mt][kc], ml[kc], at);
        at = mfma16(xl[mt][kc], mh[kc], at);
      }
#pragma unroll
      for (int i = 0; i < 4; ++i) {
        int row = mt * 16 + q * 4 + i, col = nt * 16 + r;
        u16 hh = f2bf(at[i]);
        TH[row * 72 + col] = hh;
        TL[row * 72 + col] = f2bf(at[i] - bf2f(hh));
      }
    }
  }

  // ---- Phase 1: V^T = Wv^T . X^T, a-row-tile w ----
  {
    const int mta = w;
#pragma unroll
    for (int nt = 0; nt < 3; ++nt) {
      floatx4 acc = {0.f, 0.f, 0.f, 0.f};
      acc = mfma16(wvf[0], xh[nt][0], acc);
      acc = mfma16(wvf[1], xh[nt][1], acc);
#pragma unroll
      for (int i = 0; i < 4; ++i)
        VT[(mta * 16 + q * 4 + i) * 72 + nt * 16 + r] = f2bf(acc[i]);
    }
    if (lane < 32) {  // zero K-dim pad cols g=48..63
      short8 z = {0, 0, 0, 0, 0, 0, 0, 0};
      *(short8*)(VT + (mta * 16 + (lane >> 1)) * 72 + 48 + (lane & 1) * 8) = z;
    }
  }
  __syncthreads();

  // ---- Phase 2 (waves 0-2, no further barriers): S, softmax, residual+PV ----
  if (w < 3) {
    const int mt = w;
    bf16x8 thf[2], tlf[2];
#pragma unroll
    for (int kc = 0; kc < 2; ++kc) {
      thf[kc] = *(const bf16x8*)(TH + (mt * 16 + r) * 72 + kc * 32 + q * 8);
      tlf[kc] = *(const bf16x8*)(TL + (mt * 16 + r) * 72 + kc * 32 + q * 8);
    }
    floatx4 sg[3];
#pragma unroll
    for (int gt = 0; gt < 3; ++gt) {
      floatx4 s = {0.f, 0.f, 0.f, 0.f};
#pragma unroll
      for (int kc = 0; kc < 2; ++kc) {
        s = mfma16(thf[kc], xh[gt][kc], s);   // B operand = X frags from registers
        s = mfma16(thf[kc], xl[gt][kc], s);
        s = mfma16(tlf[kc], xh[gt][kc], s);
      }
      sg[gt] = s;
    }
    const bool ok2 = (r < 8);  // col 32+r valid iff < 40
#pragma unroll
    for (int i = 0; i < 4; ++i) {
      float v0 = sg[0][i], v1 = sg[1][i], v2 = sg[2][i];
      float m = fmaxf(v0, v1);
      if (ok2) m = fmaxf(m, v2);
#pragma unroll
      for (int d = 1; d < 16; d <<= 1) m = fmaxf(m, __shfl_xor(m, d, 64));
      float p0 = __expf(v0 - m);
      float p1 = __expf(v1 - m);
      float p2 = ok2 ? __expf(v2 - m) : 0.f;
      float sum = p0 + p1 + p2;
#pragma unroll
      for (int d = 1; d < 16; d <<= 1) sum += __shfl_xor(sum, d, 64);
      float inv = 1.f / sum;
      int row = mt * 16 + q * 4 + i;
      TH[row * 72 + r]      = f2bf(p0 * inv);  // P aliases TH (own rows only)
      TH[row * 72 + 16 + r] = f2bf(p1 * inv);
      TH[row * 72 + 32 + r] = f2bf(p2 * inv);
      TH[row * 72 + 48 + r] = 0;               // K-dim pad
    }
    bf16x8 pf0 = *(const bf16x8*)(TH + (mt * 16 + r) * 72 + q * 8);
    bf16x8 pf1 = *(const bf16x8*)(TH + (mt * 16 + r) * 72 + 32 + q * 8);

    // residual directly into the PV accumulator (fp32), then P.V, relu, store
#pragma unroll
    for (int nt = 0; nt < 4; ++nt) {
      bf16x8 wr0, wr1;
      if constexpr (USEWS) {
        wr0 = *(const bf16x8*)(PRH + ((h * 4 + nt) * 2 + 0) * 512 + lane * 8);
        wr1 = *(const bf16x8*)(PRH + ((h * 4 + nt) * 2 + 1) * 512 + lane * 8);
      } else {
        bf16x8 d;
        gather2(Wres, bf, 256, h * 64 + nt * 16 + r, 0, q, wr0, d);
        gather2(Wres, bf, 256, h * 64 + nt * 16 + r, 1, q, wr1, d);
      }
      floatx4 acc = {0.f, 0.f, 0.f, 0.f};
      acc = mfma16(xh[mt][0], wr0, acc);
      acc = mfma16(xh[mt][1], wr1, acc);
      bf16x8 vb0 = *(const bf16x8*)(VT + (nt * 16 + r) * 72 + q * 8);
      bf16x8 vb1 = *(const bf16x8*)(VT + (nt * 16 + r) * 72 + 32 + q * 8);
      acc = mfma16(pf0, vb0, acc);
      acc = mfma16(pf1, vb1, acc);
#pragma unroll
      for (int i = 0; i < 4; ++i) {
        int f = mt * 16 + q * 4 + i;
        if (f < F_) {
          size_t o = ((size_t)b * F_ + f) * C_ + h * 64 + nt * 16 + r;
          float val = fmaxf(acc[i], 0.f);
          if (bf) ((u16*)outv)[o] = f2bf(val);
          else    ((float*)outv)[o] = val;
        }
      }
    }
  }
}

extern "C" void kernel_launch(void* const* d_in, const int* in_sizes, int n_in,
                              void* d_out, int out_size, void* d_ws, size_t ws_size,
                              hipStream_t stream) {
  (void)in_sizes; (void)n_in; (void)out_size;
  const void* X    = d_in[0];
  const void* Wq   = d_in[1];
  const void* Wk   = d_in[2];
  const void* Wv   = d_in[3];
  const void* Wres = d_in[4];

  bool usews = (d_ws != nullptr) && (ws_size >= 131072);
  if (usews) {
    pack_w<<<192, 256, 0, stream>>>(Wq, Wk, Wv, Wres, (u16*)d_ws);
    autoint_attn<true><<<B_ * H_, 256, 0, stream>>>(X, Wq, Wk, Wv, Wres,
                                                    (const u16*)d_ws, d_out);
  } else {
    autoint_attn<false><<<B_ * H_, 256, 0, stream>>>(X, Wq, Wk, Wv, Wres,
                                                     nullptr, d_out);
  }
}

// Round 3
// 362.717 us; speedup vs baseline: 1.0614x; 1.0614x over previous
//
#include <hip/hip_runtime.h>
#include <hip/hip_bf16.h>

typedef unsigned short u16;
typedef unsigned int u32;
using floatx4 = __attribute__((ext_vector_type(4))) float;
using short8  = __attribute__((ext_vector_type(8))) short;
using short4v = __attribute__((ext_vector_type(4))) short;
using bf16x8  = __attribute__((ext_vector_type(8))) __bf16;

#define B_ 4096
#define F_ 40
#define E_ 64
#define H_ 4
#define A_ 64
#define C_ 256

__device__ __forceinline__ float bf2f(u16 h) {
  u32 u = ((u32)h) << 16;
  return __builtin_bit_cast(float, u);
}
__device__ __forceinline__ u16 f2bf(float f) {  // RNE via hardware cvt, finite inputs
  return __builtin_bit_cast(u16, (__bf16)f);
}
__device__ __forceinline__ floatx4 mfma16(bf16x8 a, bf16x8 b, floatx4 c) {
  return __builtin_amdgcn_mfma_f32_16x16x32_bf16(a, b, c, 0, 0, 0);
}

// dtype sniff: bf16 weights have sane exponents in all 64 u16s; fp32 data's
// low halves are random bits (expect ~40/64 sane). Threshold 56 (6.6 sigma).
__device__ __forceinline__ bool detect_bf16(const void* Wq) {
  int lane = threadIdx.x & 63;
  u16 w = ((const u16*)Wq)[lane];
  int e = (w >> 7) & 0xFF;
  bool sane = (e == 0) || (e >= 96 && e <= 159);
  return __popcll(__ballot(sane)) >= 56;
}

// fallback: element gather + hi/lo split straight from source weights
__device__ __forceinline__ void gather2(const void* W, bool bf, int stride, int col,
                                        int kc, int q, bf16x8& hi, bf16x8& lo) {
  short8 h8 = {0, 0, 0, 0, 0, 0, 0, 0}, l8 = {0, 0, 0, 0, 0, 0, 0, 0};
  int e0 = kc * 32 + q * 8;
#pragma unroll
  for (int j = 0; j < 8; ++j) {
    long off = (long)(e0 + j) * stride + col;
    float v = bf ? bf2f(((const u16*)W)[off]) : ((const float*)W)[off];
    u16 hh = f2bf(v);
    h8[j] = (short)hh;
    l8[j] = (short)f2bf(v - bf2f(hh));
  }
  hi = __builtin_bit_cast(bf16x8, h8);
  lo = __builtin_bit_cast(bf16x8, l8);
}

// fallback: on-the-fly M = Wq.Wk^T fragment (head-offset pointers), hi/lo split
__device__ __forceinline__ void gatherM2(const void* Wqh, const void* Wkh, bool bf,
                                         int kc, int q, int col, bf16x8& hi, bf16x8& lo) {
  short8 h8 = {0, 0, 0, 0, 0, 0, 0, 0}, l8 = {0, 0, 0, 0, 0, 0, 0, 0};
  int e0 = kc * 32 + q * 8;
#pragma unroll
  for (int j = 0; j < 8; ++j) {
    int e1 = e0 + j;
    float acc = 0.f;
    for (int a = 0; a < 64; ++a) {
      float wq = bf ? bf2f(((const u16*)Wqh)[e1 * 64 + a]) : ((const float*)Wqh)[e1 * 64 + a];
      float wk = bf ? bf2f(((const u16*)Wkh)[col * 64 + a]) : ((const float*)Wkh)[col * 64 + a];
      acc += wq * wk;
    }
    u16 hh = f2bf(acc);
    h8[j] = (short)hh;
    l8[j] = (short)f2bf(acc - bf2f(hh));
  }
  hi = __builtin_bit_cast(bf16x8, h8);
  lo = __builtin_bit_cast(bf16x8, l8);
}

// Pack weights into MFMA fragment order (symmetric layout usable as A or B).
// ws u16 layout: [MH 16384][ML 16384][VH 16384][ResH 16384]  (65536 u16 = 128 KiB)
// M_h = Wq_h . Wk_h^T  (E x E), computed fp32-exact here, split hi/lo.
// frag(h,t,kc) elem[lane*8+j] = Mat[k = kc*32+(lane>>4)*8+j][col = t*16+(lane&15)]
__global__ void pack_w(const void* __restrict__ Wq, const void* __restrict__ Wk,
                       const void* __restrict__ Wv, const void* __restrict__ Wres,
                       u16* __restrict__ ws) {
  bool bf = detect_bf16(Wq);
  int idx = blockIdx.x * 256 + threadIdx.x;  // 0..49151
  int s = idx >> 14;                         // 0:M, 1:V, 2:Res
  int within = idx & 16383;
  int frag = within >> 9;
  int h = frag >> 3, t = (frag >> 1) & 3, kc = frag & 1;
  int pos = within & 511;
  int lane = pos >> 3, j = pos & 7;
  int q = lane >> 4, r = lane & 15;
  int e = kc * 32 + q * 8 + j;
  int col = t * 16 + r;
  if (s == 0) {
    // M[e][col] = sum_a Wq[h][e][a] * Wk[h][col][a]  (fp32 exact)
    float acc = 0.f;
    if (bf) {
      const u16* wq = (const u16*)Wq + ((long)h * 64 + e) * 64;
      const u16* wk = (const u16*)Wk + ((long)h * 64 + col) * 64;
      for (int a = 0; a < 64; ++a) acc += bf2f(wq[a]) * bf2f(wk[a]);
    } else {
      const float* wq = (const float*)Wq + ((long)h * 64 + e) * 64;
      const float* wk = (const float*)Wk + ((long)h * 64 + col) * 64;
      for (int a = 0; a < 64; ++a) acc += wq[a] * wk[a];
    }
    u16 hi = f2bf(acc);
    ws[idx] = hi;                                // MH
    ws[idx + 16384] = f2bf(acc - bf2f(hi));      // ML
  } else {
    const void* src;
    long off;
    if (s == 1) { src = Wv;   off = ((long)h * 64 + e) * 64 + col; }
    else        { src = Wres; off = (long)e * 256 + h * 64 + col; }
    float v = bf ? bf2f(((const u16*)src)[off]) : ((const float*)src)[off];
    ws[idx + 16384] = f2bf(v);  // s=1 -> [32768,49152) VH ; s=2 -> [49152,65536) ResH
  }
}

// One block = one (batch b, head h). 4 waves, 2 barriers.
// All MFMAs are computed in TRANSPOSED form so each lane's C-fragment holds 4
// CONSECUTIVE columns of one row -> packed b64/b128 LDS+global stores instead of
// scalar scatter (round-1 was VALU/DS-bound at 68% VALUBusy on exactly that).
//   T^T = M^T.X^T               (TH/TL packed writes, layout [f][a])
//   V   = X.Wv, stored transposed into VT[a][f] (packed writes)
//   S^T = X.T^T                 (lane holds a full S row -> in-register softmax,
//                                2 shuffles instead of 32)
//   O^T = V^T.P^T + Wres^T.X^T  (epilogue = 4 float4 stores instead of 16 scalar)
// Fragment layouts are symmetric (lane&15 <-> row/col, (lane>>4)*8+j <-> k), so
// the same register fragments serve as A or B operands with no data movement.
template <bool USEWS>
__global__ __launch_bounds__(256, 4) void autoint_attn(
    const void* __restrict__ Xv, const void* __restrict__ Wq,
    const void* __restrict__ Wk, const void* __restrict__ Wv,
    const void* __restrict__ Wres, const u16* __restrict__ wp,
    void* __restrict__ outv) {
  __shared__ __align__(16) u16 smem[17664];  // 35328 B -> 4 blocks/CU
  const int tid = threadIdx.x;
  // XCD-friendly decode: all 4 heads of a batch b map to blockIdx values that are
  // congruent mod 8 and adjacent in dispatch order -> X[b] stays in one XCD's L2.
  const int blk = blockIdx.x;
  const int b = ((blk >> 5) << 3) | (blk & 7);
  const int h = (blk >> 3) & 3;
  const int w = tid >> 6, lane = tid & 63;
  const int q = lane >> 4, r = lane & 15;
  const bool bf = detect_bf16(Wq);

  u16* XH = smem;             // [3 mt][2 kc][64 lane][8]  3072 u16
  u16* XL = smem + 3072;      // 3072
  u16* TH = smem + 6144;      // [48 f][72] cols a          3456 u16
  u16* TL = smem + 9600;      // [48 f][72]  (aliased by P [f][g] in phase 2)
  u16* VT = smem + 13056;     // [64 a][72] cols f (48..63 zeroed)  4608 u16

  const u16* PMH = wp;
  const u16* PML = wp + 16384;
  const u16* PVH = wp + 32768;
  const u16* PRH = wp + 49152;

  // ---- issue weight-frag global loads early (L2-hot, hide under X staging) ----
  bf16x8 mh[2], ml[2], wvf[2];
  if constexpr (USEWS) {
#pragma unroll
    for (int kc = 0; kc < 2; ++kc) {
      mh[kc]  = *(const bf16x8*)(PMH + ((h * 4 + w) * 2 + kc) * 512 + lane * 8);
      ml[kc]  = *(const bf16x8*)(PML + ((h * 4 + w) * 2 + kc) * 512 + lane * 8);
      wvf[kc] = *(const bf16x8*)(PVH + ((h * 4 + w) * 2 + kc) * 512 + lane * 8);
    }
  }

  // ---- stage X into split A-frag layout (pad rows 40..47 = 0) ----
  for (int c = tid; c < 384; c += 256) {
    short8 hi8 = {0, 0, 0, 0, 0, 0, 0, 0}, lo8 = {0, 0, 0, 0, 0, 0, 0, 0};
    int f, ec;
    if (c < 320) {
      f = c >> 3; ec = c & 7;
      if (bf) {
        hi8 = *(const short8*)((const u16*)Xv + ((size_t)b * F_ + f) * E_ + ec * 8);
      } else {
        const float* xp = (const float*)Xv + ((size_t)b * F_ + f) * E_ + ec * 8;
        float4 p0 = *(const float4*)xp;
        float4 p1 = *(const float4*)(xp + 4);
        float vals[8] = {p0.x, p0.y, p0.z, p0.w, p1.x, p1.y, p1.z, p1.w};
#pragma unroll
        for (int j = 0; j < 8; ++j) {
          u16 hh = f2bf(vals[j]);
          hi8[j] = (short)hh;
          lo8[j] = (short)f2bf(vals[j] - bf2f(hh));
        }
      }
    } else {
      f = 40 + ((c - 320) >> 3); ec = c & 7;
    }
    int mt = f >> 4, rr = f & 15, kc = ec >> 2, qq = ec & 3;
    int base = ((mt * 2 + kc) * 64 + qq * 16 + rr) * 8;
    *(short8*)(XH + base) = hi8;
    *(short8*)(XL + base) = lo8;
  }
  __syncthreads();

  bf16x8 xh[3][2], xl[3][2];
#pragma unroll
  for (int mt = 0; mt < 3; ++mt)
#pragma unroll
    for (int kc = 0; kc < 2; ++kc) {
      xh[mt][kc] = *(const bf16x8*)(XH + ((mt * 2 + kc) * 64 + lane) * 8);
      xl[mt][kc] = *(const bf16x8*)(XL + ((mt * 2 + kc) * 64 + lane) * 8);
    }

  if constexpr (!USEWS) {
    const void* Wq_p = bf ? (const void*)((const u16*)Wq + h * 4096)
                          : (const void*)((const float*)Wq + h * 4096);
    const void* Wk_p = bf ? (const void*)((const u16*)Wk + h * 4096)
                          : (const void*)((const float*)Wk + h * 4096);
    const void* Wv_p = bf ? (const void*)((const u16*)Wv + h * 4096)
                          : (const void*)((const float*)Wv + h * 4096);
    for (int kc = 0; kc < 2; ++kc) {
      gatherM2(Wq_p, Wk_p, bf, kc, q, w * 16 + r, mh[kc], ml[kc]);
      bf16x8 d;
      gather2(Wv_p, bf, 64, w * 16 + r, kc, q, wvf[kc], d);
    }
  }

  // ---- Phase 1: T^T = M^T.X^T, a-tile w; packed split writes into TH/TL ----
  {
#pragma unroll
    for (int mt = 0; mt < 3; ++mt) {
      floatx4 at = {0.f, 0.f, 0.f, 0.f};
#pragma unroll
      for (int kc = 0; kc < 2; ++kc) {
        at = mfma16(mh[kc], xh[mt][kc], at);   // Mh^T . Xh^T
        at = mfma16(ml[kc], xh[mt][kc], at);   // Ml^T . Xh^T
        at = mfma16(mh[kc], xl[mt][kc], at);   // Mh^T . Xl^T
      }
      // lane holds T[f = mt*16+r][a = w*16+q*4+i], i=0..3 consecutive
      short4v hv, lv;
#pragma unroll
      for (int i = 0; i < 4; ++i) {
        u16 hh = f2bf(at[i]);
        hv[i] = (short)hh;
        lv[i] = (short)f2bf(at[i] - bf2f(hh));
      }
      int off = (mt * 16 + r) * 72 + w * 16 + q * 4;
      *(short4v*)(TH + off) = hv;
      *(short4v*)(TL + off) = lv;
    }
  }

  // ---- Phase 1: V = X.Wv (a-tile w), stored transposed into VT[a][f] ----
  {
#pragma unroll
    for (int nt = 0; nt < 3; ++nt) {   // f-tiles
      floatx4 av = {0.f, 0.f, 0.f, 0.f};
      av = mfma16(xh[nt][0], wvf[0], av);
      av = mfma16(xh[nt][1], wvf[1], av);
      // lane holds V[f = nt*16+q*4+i][a = w*16+r]
      short4v vv;
#pragma unroll
      for (int i = 0; i < 4; ++i) vv[i] = (short)f2bf(av[i]);
      *(short4v*)(VT + (w * 16 + r) * 72 + nt * 16 + q * 4) = vv;
    }
    // zero pad cols f=48..63 (avoid NaN garbage in the PV A-operand)
    short4v z = {0, 0, 0, 0};
    *(short4v*)(VT + (w * 16 + (lane >> 2)) * 72 + 48 + (lane & 3) * 4) = z;
  }
  __syncthreads();

  // ---- Phase 2 (waves 0-2, no further barriers) ----
  if (w < 3) {
    const int mt = w;
    const int prow = (mt * 16 + r) * 72;
    bf16x8 thf[2], tlf[2];
#pragma unroll
    for (int kc = 0; kc < 2; ++kc) {
      thf[kc] = *(const bf16x8*)(TH + prow + kc * 32 + q * 8);
      tlf[kc] = *(const bf16x8*)(TL + prow + kc * 32 + q * 8);
    }
    // S^T tiles: lane holds S[f = mt*16+r][g = gt*16+q*4+i]  (full row per lane set)
    floatx4 sg[3];
#pragma unroll
    for (int gt = 0; gt < 3; ++gt) {
      floatx4 s = {0.f, 0.f, 0.f, 0.f};
#pragma unroll
      for (int kc = 0; kc < 2; ++kc) {
        s = mfma16(xh[gt][kc], thf[kc], s);   // Xh . Th^T
        s = mfma16(xl[gt][kc], thf[kc], s);   // Xl . Th^T
        s = mfma16(xh[gt][kc], tlf[kc], s);   // Xh . Tl^T
      }
      sg[gt] = s;
    }
    // in-register softmax over g; validity: gt=2 has g=32+q*4+i, valid iff q<2
    const bool ok2 = (q < 2);
    float m = fmaxf(fmaxf(sg[0][0], sg[0][1]), fmaxf(sg[0][2], sg[0][3]));
    m = fmaxf(m, fmaxf(fmaxf(sg[1][0], sg[1][1]), fmaxf(sg[1][2], sg[1][3])));
    if (ok2)
      m = fmaxf(m, fmaxf(fmaxf(sg[2][0], sg[2][1]), fmaxf(sg[2][2], sg[2][3])));
    m = fmaxf(m, __shfl_xor(m, 16, 64));
    m = fmaxf(m, __shfl_xor(m, 32, 64));
    float p0[4], p1[4], p2[4], sum = 0.f;
#pragma unroll
    for (int i = 0; i < 4; ++i) {
      p0[i] = __expf(sg[0][i] - m);
      p1[i] = __expf(sg[1][i] - m);
      p2[i] = ok2 ? __expf(sg[2][i] - m) : 0.f;
      sum += p0[i] + p1[i] + p2[i];
    }
    sum += __shfl_xor(sum, 16, 64);
    sum += __shfl_xor(sum, 32, 64);
    float inv = 1.f / sum;
    // P aliases TL (own rows only; tlf already consumed). Packed writes; cols
    // 40..47 get exact zeros from q>=2 lanes; cols 48..63 keep stale-but-finite
    // TL lo-parts which multiply the zeroed VT pad -> contribute exactly 0.
    u16* P = TL;
    short4v pk;
#pragma unroll
    for (int i = 0; i < 4; ++i) pk[i] = (short)f2bf(p0[i] * inv);
    *(short4v*)(P + prow + q * 4) = pk;
#pragma unroll
    for (int i = 0; i < 4; ++i) pk[i] = (short)f2bf(p1[i] * inv);
    *(short4v*)(P + prow + 16 + q * 4) = pk;
#pragma unroll
    for (int i = 0; i < 4; ++i) pk[i] = (short)f2bf(p2[i] * inv);
    *(short4v*)(P + prow + 32 + q * 4) = pk;

    // preload Wres frags (overlap latency with the LDS drain below)
    bf16x8 wr0[4], wr1[4];
    if constexpr (USEWS) {
#pragma unroll
      for (int nt = 0; nt < 4; ++nt) {
        wr0[nt] = *(const bf16x8*)(PRH + ((h * 4 + nt) * 2 + 0) * 512 + lane * 8);
        wr1[nt] = *(const bf16x8*)(PRH + ((h * 4 + nt) * 2 + 1) * 512 + lane * 8);
      }
    } else {
      for (int nt = 0; nt < 4; ++nt) {
        bf16x8 d;
        gather2(Wres, bf, 256, h * 64 + nt * 16 + r, 0, q, wr0[nt], d);
        gather2(Wres, bf, 256, h * 64 + nt * 16 + r, 1, q, wr1[nt], d);
      }
    }

    // same-wave cross-lane LDS RAW: drain ds_writes before reading P fragments
    __asm__ __volatile__("s_waitcnt lgkmcnt(0)" ::: "memory");
    bf16x8 pf0 = *(const bf16x8*)(P + prow + q * 8);
    bf16x8 pf1 = *(const bf16x8*)(P + prow + 32 + q * 8);

    // O^T = V^T.P^T + Wres^T.X^T, relu, packed store
#pragma unroll
    for (int nt = 0; nt < 4; ++nt) {
      floatx4 acc = {0.f, 0.f, 0.f, 0.f};
      acc = mfma16(wr0[nt], xh[mt][0], acc);
      acc = mfma16(wr1[nt], xh[mt][1], acc);
      bf16x8 vb0 = *(const bf16x8*)(VT + (nt * 16 + r) * 72 + q * 8);
      bf16x8 vb1 = *(const bf16x8*)(VT + (nt * 16 + r) * 72 + 32 + q * 8);
      acc = mfma16(vb0, pf0, acc);
      acc = mfma16(vb1, pf1, acc);
      // lane holds O[f = mt*16+r][c = h*64 + nt*16 + q*4+i], i consecutive
      int f = mt * 16 + r;
      if (f < F_) {
        size_t o = ((size_t)b * F_ + f) * C_ + h * 64 + nt * 16 + q * 4;
        if (bf) {
          short4v ov;
#pragma unroll
          for (int i = 0; i < 4; ++i) ov[i] = (short)f2bf(fmaxf(acc[i], 0.f));
          *(short4v*)((u16*)outv + o) = ov;
        } else {
          floatx4 ov;
#pragma unroll
          for (int i = 0; i < 4; ++i) ov[i] = fmaxf(acc[i], 0.f);
          *(floatx4*)((float*)outv + o) = ov;
        }
      }
    }
  }
}

extern "C" void kernel_launch(void* const* d_in, const int* in_sizes, int n_in,
                              void* d_out, int out_size, void* d_ws, size_t ws_size,
                              hipStream_t stream) {
  (void)in_sizes; (void)n_in; (void)out_size;
  const void* X    = d_in[0];
  const void* Wq   = d_in[1];
  const void* Wk   = d_in[2];
  const void* Wv   = d_in[3];
  const void* Wres = d_in[4];

  bool usews = (d_ws != nullptr) && (ws_size >= 131072);
  if (usews) {
    pack_w<<<192, 256, 0, stream>>>(Wq, Wk, Wv, Wres, (u16*)d_ws);
    autoint_attn<true><<<B_ * H_, 256, 0, stream>>>(X, Wq, Wk, Wv, Wres,
                                                    (const u16*)d_ws, d_out);
  } else {
    autoint_attn<false><<<B_ * H_, 256, 0, stream>>>(X, Wq, Wk, Wv, Wres,
                                                     nullptr, d_out);
  }
}